// Round 1
// baseline (1377.303 us; speedup 1.0000x reference)
//
#include <hip/hip_runtime.h>
#include <stdint.h>

typedef float f32x4 __attribute__((ext_vector_type(4)));
typedef int i32x4 __attribute__((ext_vector_type(4)));

#define LOG2E 1.4426950408889634f

__device__ __forceinline__ float bf2f(unsigned short u) {
  union { unsigned int i; float f; } x; x.i = ((unsigned int)u) << 16; return x.f;
}
__device__ __forceinline__ unsigned short f2bf(float f) {
  union { float f; unsigned int i; } x; x.f = f;
  unsigned int u = x.i + 0x7fffu + ((x.i >> 16) & 1u);
  return (unsigned short)(u >> 16);
}
__device__ __forceinline__ float fexp2(float x) {
#if __has_builtin(__builtin_amdgcn_exp2f)
  return __builtin_amdgcn_exp2f(x);
#else
  return exp2f(x);
#endif
}
__device__ __forceinline__ float frcp(float x) {
#if __has_builtin(__builtin_amdgcn_rcpf)
  return __builtin_amdgcn_rcpf(x);
#else
  return 1.f / x;
#endif
}
__device__ __forceinline__ float fast_exp(float x) { return fexp2(x * LOG2E); }
__device__ __forceinline__ float fast_tanh(float x) {
  float e = fexp2(x * (2.f * LOG2E));           // e^{2x}
  return 1.f - 2.f * frcp(e + 1.f);
}
__device__ __forceinline__ float fast_sigmoid(float x) {
  return frcp(1.f + fexp2(-x * LOG2E));
}

// MFMA via inline asm (gfx950 unified VGPR/AGPR file; compile-risk-free vs intrinsic type)
__device__ __forceinline__ void mfma_bf16_16x16x32(f32x4& d, i32x4 a, i32x4 b) {
  asm("v_mfma_f32_16x16x32_bf16 %0, %1, %2, %0" : "+v"(d) : "v"(a), "v"(b));
}

// global -> LDS 16B direct staging; LDS dest is wave-uniform base + lane*16 (HW adds lane term)
__device__ __forceinline__ void stage16(const unsigned short* g, unsigned short* lds_wave_base, int lane) {
#if __has_builtin(__builtin_amdgcn_global_load_lds)
  __builtin_amdgcn_global_load_lds(
      (const __attribute__((address_space(1))) unsigned int*)(uintptr_t)g,
      (__attribute__((address_space(3))) unsigned int*)(uintptr_t)lds_wave_base,
      16, 0, 0);
#else
  i32x4 v = *(const i32x4*)g;
  *(i32x4*)(lds_wave_base + lane * 8) = v;
#endif
}

// ---------------- GEMM: out[m,n] = sum_k A[m,k]*B[n,k] (+bias[n]) ----------------
// A: [M,K] bf16 row-major; B: [N,K] bf16 row-major ("B^T input" layout).
// 128x128 tile, BK=32, 256 threads (4 waves, 2x2), 4x4 16x16 fragments per wave.
#define BM 128
#define BN 128
#define BK 32

template <bool OUT_BF16, bool BIAS>
__device__ __forceinline__ void gemm_body(
    const unsigned short* __restrict__ A, const unsigned short* __restrict__ B,
    void* __restrict__ Cout, const float* __restrict__ bias,
    int K, int ldc, int nbound, int m0, int n0)
{
  __shared__ __align__(16) unsigned short lA[BM * BK];
  __shared__ __align__(16) unsigned short lB[BN * BK];
  const int tid = threadIdx.x;
  const int lane = tid & 63;
  const int w = tid >> 6;
  const int wm = w >> 1, wn = w & 1;
  const int frag_row = lane & 15;
  const int kgrp = lane >> 4;        // k-offset = kgrp*8

  f32x4 acc[4][4];
#pragma unroll
  for (int i = 0; i < 4; ++i)
#pragma unroll
    for (int j = 0; j < 4; ++j) acc[i][j] = 0.f;

  const int nK = K / BK;
  const int c0 = tid, c1 = tid + 256;     // 16B chunks; chunk c -> row c>>2, k8 = c&3
  for (int kt = 0; kt < nK; ++kt) {
    const int kb = kt * BK;
    stage16(A + (size_t)(m0 + (c0 >> 2)) * K + kb + (c0 & 3) * 8, lA + (w * 64) * 8, lane);
    stage16(A + (size_t)(m0 + (c1 >> 2)) * K + kb + (c1 & 3) * 8, lA + (256 + w * 64) * 8, lane);
    stage16(B + (size_t)(n0 + (c0 >> 2)) * K + kb + (c0 & 3) * 8, lB + (w * 64) * 8, lane);
    stage16(B + (size_t)(n0 + (c1 >> 2)) * K + kb + (c1 & 3) * 8, lB + (256 + w * 64) * 8, lane);
    __syncthreads();

    i32x4 af[4], bfr[4];
#pragma unroll
    for (int i = 0; i < 4; ++i) {
      int ra = wm * 64 + i * 16 + frag_row;
      af[i] = *(const i32x4*)&lA[ra * BK + kgrp * 8];
      int rb = wn * 64 + i * 16 + frag_row;
      bfr[i] = *(const i32x4*)&lB[rb * BK + kgrp * 8];
    }
#pragma unroll
    for (int i = 0; i < 4; ++i)
#pragma unroll
      for (int j = 0; j < 4; ++j) mfma_bf16_16x16x32(acc[i][j], af[i], bfr[j]);
    __syncthreads();
  }

  // epilogue: D col = lane&15, row = (lane>>4)*4 + r
  const int crow = (lane >> 4) * 4;
  const int ccol = lane & 15;
#pragma unroll
  for (int i = 0; i < 4; ++i) {
#pragma unroll
    for (int j = 0; j < 4; ++j) {
      int gn = n0 + wn * 64 + j * 16 + ccol;
      if (gn < nbound) {
        float bv = BIAS ? bias[gn] : 0.f;
        int gmb = m0 + wm * 64 + i * 16 + crow;
#pragma unroll
        for (int r = 0; r < 4; ++r) {
          float v = acc[i][j][r] + bv;
          if (OUT_BF16) ((unsigned short*)Cout)[(size_t)(gmb + r) * ldc + gn] = f2bf(v);
          else          ((float*)Cout)[(size_t)(gmb + r) * ldc + gn] = v;
        }
      }
    }
  }
}

__global__ __launch_bounds__(256) void gemm_bf16out_kernel(
    const unsigned short* __restrict__ A, const unsigned short* __restrict__ B,
    unsigned short* __restrict__ C, int K, int ldc) {
  gemm_body<true, false>(A, B, C, nullptr, K, ldc, 1 << 30, blockIdx.y * BM, blockIdx.x * BN);
}
__global__ __launch_bounds__(256) void gemm_f32bias_kernel(
    const unsigned short* __restrict__ A, const unsigned short* __restrict__ B,
    float* __restrict__ C, const float* __restrict__ bias, int K, int ldc, int nbound) {
  gemm_body<false, true>(A, B, C, bias, K, ldc, nbound, blockIdx.y * BM, blockIdx.x * BN);
}
__global__ __launch_bounds__(256) void gemm_gru_kernel(
    const unsigned short* __restrict__ ctx, const unsigned short* __restrict__ h,
    const unsigned short* __restrict__ wihc, const unsigned short* __restrict__ whh,
    float* __restrict__ gi, float* __restrict__ gh) {
  const unsigned short* A = blockIdx.z ? h : ctx;
  const unsigned short* B = blockIdx.z ? whh : wihc;
  float* C = blockIdx.z ? gh : gi;
  gemm_body<false, false>(A, B, C, nullptr, 512, 1536, 1 << 30, blockIdx.y * BM, blockIdx.x * BN);
}

// ---------------- setup kernels ----------------
__global__ __launch_bounds__(256) void cast_bf16_kernel(
    const float* __restrict__ src, unsigned short* __restrict__ dst, int n4) {
  int i = blockIdx.x * 256 + threadIdx.x;
  if (i < n4) {
    float4 v = ((const float4*)src)[i];
    ushort4 o;
    o.x = f2bf(v.x); o.y = f2bf(v.y); o.z = f2bf(v.z); o.w = f2bf(v.w);
    ((ushort4*)dst)[i] = o;
  }
}
// wih_c = gru_wih[:, :512] cast to bf16 packed [1536,512]
__global__ __launch_bounds__(256) void cast_wihc_kernel(
    const float* __restrict__ wih, unsigned short* __restrict__ dst) {
  int i = blockIdx.x * 256 + threadIdx.x;           // 786432
  int j = i >> 9, c = i & 511;
  dst[i] = f2bf(wih[(size_t)j * 7137 + c]);
}
// gen_w [6625,512] -> padded bf16 [6656,512] (zero rows beyond 6625)
__global__ __launch_bounds__(256) void cast_genw_kernel(
    const float* __restrict__ g, unsigned short* __restrict__ dst) {
  int i = blockIdx.x * 256 + threadIdx.x;           // 3407872
  if (i < 6656 * 512) {
    int nrow = i >> 9, c = i & 511;
    float v = (nrow < 6625) ? g[(size_t)nrow * 512 + c] : 0.f;
    dst[i] = f2bf(v);
  }
}
// ohT[t, j] = gru_wih[j, 512+t], bf16 [6625, 1536]
__global__ __launch_bounds__(256) void transpose_oh_kernel(
    const float* __restrict__ wih, unsigned short* __restrict__ dst) {
  __shared__ float tile[32][33];
  int t0 = blockIdx.x * 32;
  int j0 = blockIdx.y * 32;
  int c = threadIdx.x & 31;
  int r4 = threadIdx.x >> 5;
#pragma unroll
  for (int rr = 0; rr < 4; ++rr) {
    int r = r4 + rr * 8;
    int tcol = t0 + c;
    tile[r][c] = (tcol < 6625) ? wih[(size_t)(j0 + r) * 7137 + 512 + tcol] : 0.f;
  }
  __syncthreads();
#pragma unroll
  for (int rr = 0; rr < 4; ++rr) {
    int r = r4 + rr * 8;
    int trow = t0 + r;
    if (trow < 6625) dst[(size_t)trow * 1536 + j0 + c] = f2bf(tile[c][r]);
  }
}

// ---------------- fused attention: e -> softmax -> context ----------------
__global__ __launch_bounds__(256) void attn_kernel(
    const unsigned short* __restrict__ proj_bf,   // [B*T, 512]
    const float* __restrict__ pp,                 // [B, 512]
    const float* __restrict__ score_w,            // [512]
    const unsigned short* __restrict__ inputs_bf, // [B*T, 512]
    unsigned short* __restrict__ ctx_bf)          // [B, 512]
{
  int b = blockIdx.x;
  int tid = threadIdx.x;
  int lane = tid & 63;
  int w = tid >> 6;
  __shared__ float e_s[80];
  __shared__ float alpha_s[80];

  float ppv[8], swv[8];
  {
    const float4* p4 = (const float4*)(pp + b * 512 + lane * 8);
    *(float4*)&ppv[0] = p4[0];
    *(float4*)&ppv[4] = p4[1];
    const float4* s4 = (const float4*)(score_w + lane * 8);
    *(float4*)&swv[0] = s4[0];
    *(float4*)&swv[4] = s4[1];
  }

  for (int t = w; t < 80; t += 4) {
    union { int4 v; unsigned short us[8]; } u;
    u.v = *(const int4*)(proj_bf + (size_t)(b * 80 + t) * 512 + lane * 8);
    float acc = 0.f;
#pragma unroll
    for (int j = 0; j < 8; ++j) {
      float x = bf2f(u.us[j]) + ppv[j];
      acc += fast_tanh(x) * swv[j];
    }
#pragma unroll
    for (int m = 32; m >= 1; m >>= 1) acc += __shfl_xor(acc, m, 64);
    if (lane == 0) e_s[t] = acc;
  }
  __syncthreads();
  if (w == 0) {
    float v0 = e_s[lane];
    float v1 = (lane < 16) ? e_s[64 + lane] : -1e30f;
    float mx = fmaxf(v0, v1);
#pragma unroll
    for (int m = 32; m >= 1; m >>= 1) mx = fmaxf(mx, __shfl_xor(mx, m, 64));
    float a0 = fast_exp(v0 - mx);
    float a1 = (lane < 16) ? fast_exp(v1 - mx) : 0.f;
    float sm = a0 + a1;
#pragma unroll
    for (int m = 32; m >= 1; m >>= 1) sm += __shfl_xor(sm, m, 64);
    float inv = frcp(sm);
    alpha_s[lane] = a0 * inv;
    if (lane < 16) alpha_s[64 + lane] = a1 * inv;
  }
  __syncthreads();
  float acc0 = 0.f, acc1 = 0.f;
  const unsigned short* ip = inputs_bf + (size_t)b * 80 * 512;
#pragma unroll 8
  for (int t = 0; t < 80; ++t) {
    float al = alpha_s[t];
    acc0 += al * bf2f(ip[t * 512 + tid]);
    acc1 += al * bf2f(ip[t * 512 + 256 + tid]);
  }
  ctx_bf[b * 512 + tid] = f2bf(acc0);
  ctx_bf[b * 512 + 256 + tid] = f2bf(acc1);
}

// ---------------- GRU cell elementwise ----------------
__global__ __launch_bounds__(256) void gru_cell_kernel(
    const float* __restrict__ gi, const float* __restrict__ gh,
    const unsigned short* __restrict__ ohT,
    const int* __restrict__ targets,
    const float* __restrict__ bih, const float* __restrict__ bhh,
    unsigned short* __restrict__ h_bf, unsigned short* __restrict__ hid_bf, int s)
{
  int idx = blockIdx.x * 256 + threadIdx.x;   // 131072
  int b = idx >> 9, j = idx & 511;
  int tgt = targets[b * 25 + s];
  const unsigned short* oh = ohT + (size_t)tgt * 1536;
  const float* gib = gi + b * 1536;
  const float* ghb = gh + b * 1536;
  float ir  = gib[j]        + bf2f(oh[j])        + bih[j];
  float iz  = gib[512 + j]  + bf2f(oh[512 + j])  + bih[512 + j];
  float in_ = gib[1024 + j] + bf2f(oh[1024 + j]) + bih[1024 + j];
  float hr  = ghb[j]        + bhh[j];
  float hz  = ghb[512 + j]  + bhh[512 + j];
  float hn  = ghb[1024 + j] + bhh[1024 + j];
  float r = fast_sigmoid(ir + hr);
  float z = fast_sigmoid(iz + hz);
  float n = fast_tanh(in_ + r * hn);
  float h = (1.f - z) * n + z * bf2f(h_bf[idx]);
  unsigned short hb = f2bf(h);
  h_bf[idx] = hb;
  hid_bf[(size_t)(b * 25 + s) * 512 + j] = hb;
}

extern "C" void kernel_launch(void* const* d_in, const int* in_sizes, int n_in,
                              void* d_out, int out_size, void* d_ws, size_t ws_size,
                              hipStream_t stream) {
  (void)in_sizes; (void)n_in; (void)out_size; (void)ws_size;
  const float* inputs  = (const float*)d_in[0];
  const int*   targets = (const int*)d_in[1];
  const float* i2h_w   = (const float*)d_in[3];
  const float* h2h_w   = (const float*)d_in[4];
  const float* h2h_b   = (const float*)d_in[5];
  const float* score_w = (const float*)d_in[6];
  const float* gru_wih = (const float*)d_in[7];
  const float* gru_whh = (const float*)d_in[8];
  const float* gru_bih = (const float*)d_in[9];
  const float* gru_bhh = (const float*)d_in[10];
  const float* gen_w   = (const float*)d_in[11];
  const float* gen_b   = (const float*)d_in[12];
  float* out = (float*)d_out;

  char* ws = (char*)d_ws;
  size_t off = 0;
  auto alloc = [&](size_t bytes) {
    char* p = ws + off;
    off += (bytes + 255) & ~(size_t)255;
    return p;
  };
  unsigned short* inputs_bf = (unsigned short*)alloc(10485760ull * 2);
  unsigned short* proj_bf   = (unsigned short*)alloc(10485760ull * 2);
  unsigned short* i2h_bf    = (unsigned short*)alloc(262144ull * 2);
  unsigned short* h2h_bf    = (unsigned short*)alloc(262144ull * 2);
  unsigned short* whh_bf    = (unsigned short*)alloc(786432ull * 2);
  unsigned short* wihc_bf   = (unsigned short*)alloc(786432ull * 2);
  unsigned short* ohT_bf    = (unsigned short*)alloc(10176000ull * 2);
  unsigned short* genw_bf   = (unsigned short*)alloc(3407872ull * 2);
  float*          pp        = (float*)alloc(131072ull * 4);
  unsigned short* ctx_bf    = (unsigned short*)alloc(131072ull * 2);
  float*          gi        = (float*)alloc(393216ull * 4);
  float*          gh        = (float*)alloc(393216ull * 4);
  unsigned short* h_bf      = (unsigned short*)alloc(131072ull * 2);
  unsigned short* hid_bf    = (unsigned short*)alloc(3276800ull * 2);

  // setup
  cast_bf16_kernel<<<10240, 256, 0, stream>>>(inputs, inputs_bf, 2621440);
  cast_bf16_kernel<<<256, 256, 0, stream>>>(i2h_w, i2h_bf, 65536);
  cast_bf16_kernel<<<256, 256, 0, stream>>>(h2h_w, h2h_bf, 65536);
  cast_bf16_kernel<<<768, 256, 0, stream>>>(gru_whh, whh_bf, 196608);
  cast_wihc_kernel<<<3072, 256, 0, stream>>>(gru_wih, wihc_bf);
  transpose_oh_kernel<<<dim3(208, 48), 256, 0, stream>>>(gru_wih, ohT_bf);
  cast_genw_kernel<<<13312, 256, 0, stream>>>(gen_w, genw_bf);
  // batch_H_proj = inputs @ i2h_w.T   [20480, 512]
  gemm_bf16out_kernel<<<dim3(4, 160), 256, 0, stream>>>(inputs_bf, i2h_bf, proj_bf, 512, 512);
  hipMemsetAsync(h_bf, 0, 131072 * 2, stream);

  for (int s = 0; s < 25; ++s) {
    // pp = h @ h2h_w.T + h2h_b
    gemm_f32bias_kernel<<<dim3(4, 2), 256, 0, stream>>>(h_bf, h2h_bf, pp, h2h_b, 512, 512, 512);
    attn_kernel<<<256, 256, 0, stream>>>(proj_bf, pp, score_w, inputs_bf, ctx_bf);
    gemm_gru_kernel<<<dim3(12, 2, 2), 256, 0, stream>>>(ctx_bf, h_bf, wihc_bf, whh_bf, gi, gh);
    gru_cell_kernel<<<512, 256, 0, stream>>>(gi, gh, ohT_bf, targets, gru_bih, gru_bhh, h_bf, hid_bf, s);
  }
  // probs = hiddens @ gen_w.T + gen_b  [6400, 6625]
  gemm_f32bias_kernel<<<dim3(52, 50), 256, 0, stream>>>(hid_bf, genw_bf, out, gen_b, 512, 6625, 6625);
}